// Round 5
// baseline (929.658 us; speedup 1.0000x reference)
//
#include <hip/hip_runtime.h>
#include <hip/hip_bf16.h>
#include <math.h>

#define S 4096
#define HQ 8
#define NKVH 4
#define D 256
#define HID 2304
#define SW 2048
#define QDIM 2048
#define KVDIM 1024
#define SCALE 0.0625f
#define SOFTCAP 50.0f

typedef __attribute__((ext_vector_type(4))) float f32x4;
typedef __attribute__((ext_vector_type(8))) short short8;   // 8 bf16 = 4 VGPRs (MFMA A/B frag)

__device__ __forceinline__ float bf2f(unsigned v) { return __uint_as_float(v << 16); }
__device__ __forceinline__ unsigned f2bf(float f) {
    unsigned u = __float_as_uint(f);
    return (u + 0x7fffu + ((u >> 16) & 1u)) >> 16;   // round-to-nearest-even
}

__device__ __forceinline__ void store_c(float* p, float v) { *p = v; }
__device__ __forceinline__ void store_c(unsigned short* p, float v) { *p = (unsigned short)f2bf(v); }

// async global->LDS, 16B per lane; lds dst must be wave-uniform base (HW adds lane*16)
__device__ __forceinline__ void glls16(const void* g, void* l) {
    __builtin_amdgcn_global_load_lds(
        (const __attribute__((address_space(1))) unsigned int*)g,
        (__attribute__((address_space(3))) unsigned int*)l, 16, 0, 0);
}

// ---------------------------------------------------------------------------
// fp32 -> bf16 elementwise (float4 per thread)
// ---------------------------------------------------------------------------
__global__ __launch_bounds__(256) void cvt_bf16(const float* __restrict__ in,
                                                unsigned short* __restrict__ out)
{
    int i = blockIdx.x * 256 + threadIdx.x;
    float4 v = ((const float4*)in)[i];
    uint2 o;
    o.x = f2bf(v.x) | (f2bf(v.y) << 16);
    o.y = f2bf(v.z) | (f2bf(v.w) << 16);
    ((uint2*)out)[i] = o;
}

// ---------------------------------------------------------------------------
// C[M][N] = A[M][K] @ B[N][K]^T, bf16 in, fp32 accumulate, TC out.
// 128x128 tile, BK=32, 256 threads (2x2 waves, 4x4 MFMA tiles each).
// LDS fragment-major: frag f = 16 rows x 32 k, stored as 64 lanes x 16 B
// contiguous (1 KiB); staged via global_load_lds (global side permuted).
// ---------------------------------------------------------------------------
template <typename TC>
__global__ __launch_bounds__(256) void bf16_gemm_bt(const unsigned short* __restrict__ A,
                                                    const unsigned short* __restrict__ B,
                                                    TC* __restrict__ C,
                                                    int M, int N, int K)
{
    __shared__ unsigned short As[128 * 32];   // 8 frags x 1 KiB = 8 KiB
    __shared__ unsigned short Bs[128 * 32];
    const int t = threadIdx.x;
    const int m0 = blockIdx.y * 128, n0 = blockIdx.x * 128;
    const int w = t >> 6, lid = t & 63, n16 = lid & 15, quad = lid >> 4;
    const int wm = (w >> 1) * 64, wn = (w & 1) * 64;
    const int lkc = (lid >> 4) * 8;           // k-chunk within frag

    f32x4 acc[4][4] = {};

    for (int k0 = 0; k0 < K; k0 += 32) {
        __syncthreads();
        #pragma unroll
        for (int it = 0; it < 2; ++it) {
            int frag = it * 4 + w;                    // wave-uniform
            int row  = frag * 16 + n16;
            glls16(A + (size_t)(m0 + row) * K + k0 + lkc, As + frag * 512);
            glls16(B + (size_t)(n0 + row) * K + k0 + lkc, Bs + frag * 512);
        }
        asm volatile("s_waitcnt vmcnt(0)" ::: "memory");
        __syncthreads();
        short8 af[4], bfr[4];
        #pragma unroll
        for (int x = 0; x < 4; ++x) {
            af[x]  = *(const short8*)(As + ((wm >> 4) + x) * 512 + lid * 8);
            bfr[x] = *(const short8*)(Bs + ((wn >> 4) + x) * 512 + lid * 8);
        }
        #pragma unroll
        for (int i = 0; i < 4; ++i)
            #pragma unroll
            for (int j = 0; j < 4; ++j)
                acc[i][j] = __builtin_amdgcn_mfma_f32_16x16x32_bf16(af[i], bfr[j], acc[i][j], 0, 0, 0);
    }

    // C/D layout: col = lane&15, row = quad*4 + reg
    #pragma unroll
    for (int i = 0; i < 4; ++i) {
        #pragma unroll
        for (int j = 0; j < 4; ++j) {
            int rbase = m0 + wm + i * 16 + quad * 4;
            int col   = n0 + wn + j * 16 + n16;
            #pragma unroll
            for (int rg = 0; rg < 4; ++rg)
                store_c(C + (size_t)(rbase + rg) * N + col, acc[i][j][rg]);
        }
    }
}

// ---------------------------------------------------------------------------
// RoPE: read bf16 Q/K (pre-RoPE), write bf16 Qb/Kb (SCALE folded into Q).
// ---------------------------------------------------------------------------
__global__ __launch_bounds__(256) void rope_kernel(const unsigned short* __restrict__ Qf,
                                                   const unsigned short* __restrict__ Kf,
                                                   unsigned short* __restrict__ Qb,
                                                   unsigned short* __restrict__ Kb,
                                                   const int* __restrict__ pos_ids)
{
    int id   = blockIdx.x * 256 + threadIdx.x;   // S * 12 * 128 threads
    int d    = id & 127;
    int rest = id >> 7;
    int hh   = rest % 12;
    int i    = rest / 12;
    float pos = (float)pos_ids[i];
    float inv = __expf((float)d * (-9.210340371976184f / 128.0f));   // 10000^(-d/128)
    float ang = pos * inv;
    float sn, cs;
    sincosf(ang, &sn, &cs);
    if (hh < HQ) {
        const unsigned short* p = Qf + (size_t)i * QDIM + hh * D + d;
        float x0 = bf2f(p[0]), x1 = bf2f(p[128]);
        unsigned short* q = Qb + (size_t)i * QDIM + hh * D + d;
        q[0]   = (unsigned short)f2bf((x0 * cs - x1 * sn) * SCALE);
        q[128] = (unsigned short)f2bf((x1 * cs + x0 * sn) * SCALE);
    } else {
        const unsigned short* p = Kf + (size_t)i * KVDIM + (hh - HQ) * D + d;
        float x0 = bf2f(p[0]), x1 = bf2f(p[128]);
        unsigned short* k = Kb + (size_t)i * KVDIM + (hh - HQ) * D + d;
        k[0]   = (unsigned short)f2bf(x0 * cs - x1 * sn);
        k[128] = (unsigned short)f2bf(x1 * cs + x0 * sn);
    }
}

// ---------------------------------------------------------------------------
// V transpose: Vf [S][KVDIM] bf16 -> Vt [KVDIM][S] bf16.
// ---------------------------------------------------------------------------
__global__ __launch_bounds__(256) void transpose_v(const unsigned short* __restrict__ Vf,
                                                   unsigned short* __restrict__ Vt)
{
    __shared__ float tile[64][65];
    const int s0 = blockIdx.x * 64, d0 = blockIdx.y * 64;
    const int t = threadIdx.x;
    #pragma unroll
    for (int it = 0; it < 4; ++it) {
        int flat = it * 256 + t;
        int r  = flat >> 4;          // s-row 0..63
        int c4 = (flat & 15) * 4;    // d-col
        uint2 v = *(const uint2*)(Vf + (size_t)(s0 + r) * KVDIM + d0 + c4);
        tile[r][c4 + 0] = bf2f(v.x & 0xffffu); tile[r][c4 + 1] = bf2f(v.x >> 16);
        tile[r][c4 + 2] = bf2f(v.y & 0xffffu); tile[r][c4 + 3] = bf2f(v.y >> 16);
    }
    __syncthreads();
    #pragma unroll
    for (int it = 0; it < 4; ++it) {
        int flat = it * 256 + t;
        int dr  = flat >> 4;         // d-row
        int sc4 = (flat & 15) * 4;   // s-col
        uint2 o;
        o.x = f2bf(tile[sc4 + 0][dr]) | (f2bf(tile[sc4 + 1][dr]) << 16);
        o.y = f2bf(tile[sc4 + 2][dr]) | (f2bf(tile[sc4 + 3][dr]) << 16);
        *(uint2*)(Vt + (size_t)(d0 + dr) * S + s0 + sc4) = o;
    }
}

// ---------------------------------------------------------------------------
// MFMA flash attention. Block = 256 threads (4 waves), 128 q-rows, 1 head.
// Wave w: q rows [i0+32w, i0+32w+32) (2 m-tiles). KV tiles of 64 keys.
// K/V staged via global_load_lds into fragment-major LDS (conflict-free
// contiguous ds_read_b128); P LDS round-trip (C-layout -> A-layout).
// LDS = 32K (K) + 32K (V) + 16K (P) = 80 KiB -> 2 blocks/CU.
// ---------------------------------------------------------------------------
__global__ __launch_bounds__(256, 2) void attn_kernel(const unsigned short* __restrict__ Qb,
                                                      const unsigned short* __restrict__ Kb,
                                                      const unsigned short* __restrict__ Vt,
                                                      unsigned short* __restrict__ O)
{
    __shared__ unsigned short Ks[64 * 256];   // frag(nt*8+ks): K[key=nt*16+n16][k=ks*32+quad*8]
    __shared__ unsigned short Vs[256 * 64];   // frag(dt*2+ks2): Vt[d=dt*16+n16][key=ks2*32+quad*8]
    __shared__ unsigned short Ps[4 * 2048];   // per-wave frag(mt*2+ks2): P[m][key]
    const int t = threadIdx.x;
    const int h = blockIdx.y, kvh = h >> 1;
    const int i0 = blockIdx.x * 128;
    const int w = t >> 6, lid = t & 63, n16 = lid & 15, quad = lid >> 4;
    const int qbase = i0 + w * 32;
    unsigned short* Pw = Ps + w * 2048;

    // Q A-frags in registers: qf[mt][ks]
    short8 qf[2][8];
    #pragma unroll
    for (int mt = 0; mt < 2; ++mt)
        #pragma unroll
        for (int ks = 0; ks < 8; ++ks)
            qf[mt][ks] = *(const short8*)(Qb + (size_t)(qbase + mt * 16 + n16) * QDIM + h * D + ks * 32 + quad * 8);

    float m_old[2][4], l[2][4];
    #pragma unroll
    for (int mt = 0; mt < 2; ++mt)
        #pragma unroll
        for (int rg = 0; rg < 4; ++rg) { m_old[mt][rg] = -INFINITY; l[mt][rg] = 0.f; }
    f32x4 Oacc[2][16] = {};

    const int jt_min = (i0 >= SW) ? ((i0 - (SW - 1)) >> 6) : 0;
    const int jt_max = (i0 + 127) >> 6;

    for (int jt = jt_min; jt <= jt_max; ++jt) {
        const int j0 = jt * 64;
        __syncthreads();
        #pragma unroll
        for (int it = 0; it < 8; ++it) {          // stage K (32 KiB)
            int frag = it * 4 + w;                // wave-uniform
            int nt = frag >> 3, ks = frag & 7;
            glls16(Kb + (size_t)(j0 + nt * 16 + n16) * KVDIM + kvh * D + ks * 32 + quad * 8,
                   Ks + frag * 512);
        }
        #pragma unroll
        for (int it = 0; it < 8; ++it) {          // stage V^T (32 KiB)
            int frag = it * 4 + w;
            int dt = frag >> 1, ks2 = frag & 1;
            glls16(Vt + (size_t)(kvh * D + dt * 16 + n16) * S + j0 + ks2 * 32 + quad * 8,
                   Vs + frag * 512);
        }
        asm volatile("s_waitcnt vmcnt(0)" ::: "memory");
        __syncthreads();

        // ---- S = Q K^T
        f32x4 sc[2][4] = {};
        #pragma unroll
        for (int ks = 0; ks < 8; ++ks) {
            #pragma unroll
            for (int nt = 0; nt < 4; ++nt) {
                short8 kf = *(const short8*)(Ks + (nt * 8 + ks) * 512 + lid * 8);
                sc[0][nt] = __builtin_amdgcn_mfma_f32_16x16x32_bf16(qf[0][ks], kf, sc[0][nt], 0, 0, 0);
                sc[1][nt] = __builtin_amdgcn_mfma_f32_16x16x32_bf16(qf[1][ks], kf, sc[1][nt], 0, 0, 0);
            }
        }

        // ---- softcap + mask (C layout: key = nt*16+n16, q-row = mt*16+quad*4+rg)
        #pragma unroll
        for (int mt = 0; mt < 2; ++mt) {
            #pragma unroll
            for (int nt = 0; nt < 4; ++nt) {
                int j = j0 + nt * 16 + n16;
                #pragma unroll
                for (int rg = 0; rg < 4; ++rg) {
                    int iq = qbase + mt * 16 + quad * 4 + rg;
                    float x = sc[mt][nt][rg];
                    float e = __expf(x * (2.0f / SOFTCAP));
                    x = SOFTCAP * (1.0f - 2.0f / (e + 1.0f));    // 50*tanh(x/50)
                    bool ok = (j <= iq) && (iq - j < SW);
                    sc[mt][nt][rg] = ok ? x : -1e9f;
                }
            }
        }

        // ---- online softmax per q-row
        float alpha[2][4];
        #pragma unroll
        for (int mt = 0; mt < 2; ++mt) {
            #pragma unroll
            for (int rg = 0; rg < 4; ++rg) {
                float mx = fmaxf(fmaxf(sc[mt][0][rg], sc[mt][1][rg]),
                                 fmaxf(sc[mt][2][rg], sc[mt][3][rg]));
                mx = fmaxf(mx, __shfl_xor(mx, 1));
                mx = fmaxf(mx, __shfl_xor(mx, 2));
                mx = fmaxf(mx, __shfl_xor(mx, 4));
                mx = fmaxf(mx, __shfl_xor(mx, 8));
                float mnew = fmaxf(m_old[mt][rg], mx);
                alpha[mt][rg] = __expf(m_old[mt][rg] - mnew);   // -inf -> 0 first tile
                m_old[mt][rg] = mnew;
            }
        }
        // ---- p = exp(s-m), write P to LDS in A-frag order, accumulate l
        #pragma unroll
        for (int mt = 0; mt < 2; ++mt) {
            #pragma unroll
            for (int rg = 0; rg < 4; ++rg) {
                float rs = 0.f;
                #pragma unroll
                for (int nt = 0; nt < 4; ++nt) {
                    float pv = __expf(sc[mt][nt][rg] - m_old[mt][rg]);
                    // frag(mt, ks2=nt>>1); lane' = (quad*4+rg) + 16*((nt&1)*2 + (n16>>3)); elem = n16&7
                    Pw[(mt * 2 + (nt >> 1)) * 512
                       + (quad * 4 + rg + 16 * ((nt & 1) * 2 + (n16 >> 3))) * 8
                       + (n16 & 7)] = (unsigned short)f2bf(pv);
                    rs += pv;
                }
                rs += __shfl_xor(rs, 1); rs += __shfl_xor(rs, 2);
                rs += __shfl_xor(rs, 4); rs += __shfl_xor(rs, 8);
                l[mt][rg] = l[mt][rg] * alpha[mt][rg] + rs;
            }
        }
        #pragma unroll
        for (int mt = 0; mt < 2; ++mt)
            #pragma unroll
            for (int dt = 0; dt < 16; ++dt)
                #pragma unroll
                for (int rg = 0; rg < 4; ++rg)
                    Oacc[mt][dt][rg] *= alpha[mt][rg];

        asm volatile("s_waitcnt lgkmcnt(0)" ::: "memory");   // P writes visible (wave-private)

        // ---- O += P V
        #pragma unroll
        for (int ks2 = 0; ks2 < 2; ++ks2) {
            short8 pf0 = *(const short8*)(Pw + (0 * 2 + ks2) * 512 + lid * 8);
            short8 pf1 = *(const short8*)(Pw + (1 * 2 + ks2) * 512 + lid * 8);
            #pragma unroll
            for (int dt = 0; dt < 16; ++dt) {
                short8 vf = *(const short8*)(Vs + (dt * 2 + ks2) * 512 + lid * 8);
                Oacc[0][dt] = __builtin_amdgcn_mfma_f32_16x16x32_bf16(pf0, vf, Oacc[0][dt], 0, 0, 0);
                Oacc[1][dt] = __builtin_amdgcn_mfma_f32_16x16x32_bf16(pf1, vf, Oacc[1][dt], 0, 0, 0);
            }
        }
    }

    #pragma unroll
    for (int mt = 0; mt < 2; ++mt)
        #pragma unroll
        for (int rg = 0; rg < 4; ++rg) l[mt][rg] = 1.0f / l[mt][rg];
    #pragma unroll
    for (int mt = 0; mt < 2; ++mt) {
        #pragma unroll
        for (int dt = 0; dt < 16; ++dt) {
            int col = h * D + dt * 16 + n16;
            #pragma unroll
            for (int rg = 0; rg < 4; ++rg) {
                int row = qbase + mt * 16 + quad * 4 + rg;
                O[(size_t)row * QDIM + col] = (unsigned short)f2bf(Oacc[mt][dt][rg] * l[mt][rg]);
            }
        }
    }
}

extern "C" void kernel_launch(void* const* d_in, const int* in_sizes, int n_in,
                              void* d_out, int out_size, void* d_ws, size_t ws_size,
                              hipStream_t stream) {
    const float* hidden = (const float*)d_in[0];
    // d_in[1] = attention_mask: recomputed analytically, not read
    const float* Wq = (const float*)d_in[2];
    const float* Wk = (const float*)d_in[3];
    const float* Wv = (const float*)d_in[4];
    const float* Wo = (const float*)d_in[5];
    const int* pos = (const int*)d_in[6];
    float* out = (float*)d_out;

    char* ws = (char*)d_ws;
    unsigned short* Qf = (unsigned short*)(ws);                       // [S][2048] bf16, 16 MiB
    unsigned short* Kf = (unsigned short*)(ws + (size_t)(16 << 20));  // [S][1024] bf16,  8 MiB
    unsigned short* Vf = (unsigned short*)(ws + (size_t)(24 << 20));  // [S][1024] bf16,  8 MiB
    unsigned short* Qb = (unsigned short*)(ws + (size_t)(32 << 20));  // 16 MiB
    unsigned short* Kb = (unsigned short*)(ws + (size_t)(48 << 20));  //  8 MiB
    unsigned short* Vt = (unsigned short*)(ws + (size_t)(56 << 20));  //  8 MiB
    unsigned short* Hb = (unsigned short*)(ws + (size_t)(64 << 20));  // [S][2304] bf16, 18 MiB
    unsigned short* Wb = (unsigned short*)(ws + (size_t)(82 << 20));  // weight buf (reused), 9 MiB
    unsigned short* Oa = (unsigned short*)(ws);                       // aliases Qf (dead after rope)

    cvt_bf16<<<(S * HID) / 1024, 256, 0, stream>>>(hidden, Hb);

    cvt_bf16<<<(QDIM * HID) / 1024, 256, 0, stream>>>(Wq, Wb);
    bf16_gemm_bt<unsigned short><<<dim3(QDIM / 128, S / 128), 256, 0, stream>>>(Hb, Wb, Qf, S, QDIM, HID);
    cvt_bf16<<<(KVDIM * HID) / 1024, 256, 0, stream>>>(Wk, Wb);
    bf16_gemm_bt<unsigned short><<<dim3(KVDIM / 128, S / 128), 256, 0, stream>>>(Hb, Wb, Kf, S, KVDIM, HID);
    cvt_bf16<<<(KVDIM * HID) / 1024, 256, 0, stream>>>(Wv, Wb);
    bf16_gemm_bt<unsigned short><<<dim3(KVDIM / 128, S / 128), 256, 0, stream>>>(Hb, Wb, Vf, S, KVDIM, HID);

    rope_kernel<<<(S * 12 * 128) / 256, 256, 0, stream>>>(Qf, Kf, Qb, Kb, pos);
    transpose_v<<<dim3(S / 64, KVDIM / 64), 256, 0, stream>>>(Vf, Vt);

    attn_kernel<<<dim3(S / 128, HQ), 256, 0, stream>>>(Qb, Kb, Vt, Oa);

    cvt_bf16<<<(HID * QDIM) / 1024, 256, 0, stream>>>(Wo, Wb);
    bf16_gemm_bt<float><<<dim3(HID / 128, S / 128), 256, 0, stream>>>(Oa, Wb, out, S, HID, QDIM);
}

// Round 6
// 792.147 us; speedup vs baseline: 1.1736x; 1.1736x over previous
//
#include <hip/hip_runtime.h>
#include <hip/hip_bf16.h>
#include <math.h>

#define S 4096
#define HQ 8
#define NKVH 4
#define D 256
#define HID 2304
#define SW 2048
#define QDIM 2048
#define KVDIM 1024
#define SCALE 0.0625f
#define SOFTCAP 50.0f

typedef __attribute__((ext_vector_type(4))) float f32x4;
typedef __attribute__((ext_vector_type(8))) short short8;   // 8 bf16 = 4 VGPRs (MFMA A/B frag)

__device__ __forceinline__ float bf2f(unsigned v) { return __uint_as_float(v << 16); }
__device__ __forceinline__ unsigned f2bf(float f) {
    unsigned u = __float_as_uint(f);
    return (u + 0x7fffu + ((u >> 16) & 1u)) >> 16;   // round-to-nearest-even
}

__device__ __forceinline__ void store_c(float* p, float v) { *p = v; }
__device__ __forceinline__ void store_c(unsigned short* p, float v) { *p = (unsigned short)f2bf(v); }

// async global->LDS, 16B per lane; lds dst is wave-uniform base (HW adds lane*16)
__device__ __forceinline__ void glls16(const void* g, void* l) {
    __builtin_amdgcn_global_load_lds(
        (const __attribute__((address_space(1))) unsigned int*)g,
        (__attribute__((address_space(3))) unsigned int*)l, 16, 0, 0);
}

// ---------------------------------------------------------------------------
// fp32 -> bf16 elementwise (float4 per thread)
// ---------------------------------------------------------------------------
__global__ __launch_bounds__(256) void cvt_bf16(const float* __restrict__ in,
                                                unsigned short* __restrict__ out)
{
    int i = blockIdx.x * 256 + threadIdx.x;
    float4 v = ((const float4*)in)[i];
    uint2 o;
    o.x = f2bf(v.x) | (f2bf(v.y) << 16);
    o.y = f2bf(v.z) | (f2bf(v.w) << 16);
    ((uint2*)out)[i] = o;
}

// ---------------------------------------------------------------------------
// C[M][N] = A[M][K] @ B[N][K]^T, bf16 in, fp32 accumulate, TC out.
// 128x128 tile, BK=64, 256 threads (2x2 waves, 4x4 MFMA tiles, 2 k-substeps).
// Double-buffered LDS, fragment-major (frag = 16 rows x 32 k = 1 KiB, one
// conflict-free contiguous ds_read_b128 wave read), staged via
// global_load_lds; prefetch k+1 while computing k; ONE barrier per k-step.
// ---------------------------------------------------------------------------
template <typename TC>
__global__ __launch_bounds__(256) void bf16_gemm_bt(const unsigned short* __restrict__ A,
                                                    const unsigned short* __restrict__ B,
                                                    TC* __restrict__ C,
                                                    int M, int N, int K)
{
    __shared__ unsigned short As[2][16 * 512];   // 16 frags x 1 KiB per buffer
    __shared__ unsigned short Bs[2][16 * 512];
    const int t = threadIdx.x;
    const int m0 = blockIdx.y * 128, n0 = blockIdx.x * 128;
    const int w = t >> 6, lid = t & 63, n16 = lid & 15, quad = lid >> 4;
    const int wm = (w >> 1) * 64, wn = (w & 1) * 64;

    f32x4 acc[4][4] = {};

    // stage buffer `buf` with k-panel starting at k0 (8 glls per wave)
    auto stage = [&](int buf, int k0) {
        #pragma unroll
        for (int it = 0; it < 4; ++it) {
            int f  = it * 4 + w;              // wave-uniform frag id 0..15
            int fm = f >> 1, fk = f & 1;
            const size_t goff = (size_t)(fm * 16 + n16) * K + k0 + fk * 32 + quad * 8;
            glls16(A + (size_t)m0 * K + goff, &As[buf][f * 512]);
            glls16(B + (size_t)n0 * K + goff, &Bs[buf][f * 512]);
        }
    };

    const int nk = K / 64;
    stage(0, 0);
    int cur = 0;
    for (int kk = 0; kk < nk; ++kk) {
        asm volatile("s_waitcnt vmcnt(0)" ::: "memory");   // own staging done
        __syncthreads();                                   // everyone's visible
        if (kk + 1 < nk) stage(cur ^ 1, (kk + 1) * 64);    // prefetch next panel
        #pragma unroll
        for (int ks = 0; ks < 2; ++ks) {
            short8 af[4], bfr[4];
            #pragma unroll
            for (int x = 0; x < 4; ++x) {
                af[x]  = *(const short8*)(&As[cur][(((wm >> 4) + x) * 2 + ks) * 512 + lid * 8]);
                bfr[x] = *(const short8*)(&Bs[cur][(((wn >> 4) + x) * 2 + ks) * 512 + lid * 8]);
            }
            #pragma unroll
            for (int i = 0; i < 4; ++i)
                #pragma unroll
                for (int j = 0; j < 4; ++j)
                    acc[i][j] = __builtin_amdgcn_mfma_f32_16x16x32_bf16(af[i], bfr[j], acc[i][j], 0, 0, 0);
        }
        cur ^= 1;
    }

    // C/D layout: col = lane&15, row = quad*4 + reg
    #pragma unroll
    for (int i = 0; i < 4; ++i) {
        #pragma unroll
        for (int j = 0; j < 4; ++j) {
            int rbase = m0 + wm + i * 16 + quad * 4;
            int col   = n0 + wn + j * 16 + n16;
            #pragma unroll
            for (int rg = 0; rg < 4; ++rg)
                store_c(C + (size_t)(rbase + rg) * N + col, acc[i][j][rg]);
        }
    }
}

// ---------------------------------------------------------------------------
// RoPE: read bf16 Q/K (pre-RoPE), write bf16 Qb/Kb (SCALE folded into Q).
// ---------------------------------------------------------------------------
__global__ __launch_bounds__(256) void rope_kernel(const unsigned short* __restrict__ Qf,
                                                   const unsigned short* __restrict__ Kf,
                                                   unsigned short* __restrict__ Qb,
                                                   unsigned short* __restrict__ Kb,
                                                   const int* __restrict__ pos_ids)
{
    int id   = blockIdx.x * 256 + threadIdx.x;   // S * 12 * 128 threads
    int d    = id & 127;
    int rest = id >> 7;
    int hh   = rest % 12;
    int i    = rest / 12;
    float pos = (float)pos_ids[i];
    float inv = __expf((float)d * (-9.210340371976184f / 128.0f));   // 10000^(-d/128)
    float ang = pos * inv;
    float sn, cs;
    sincosf(ang, &sn, &cs);
    if (hh < HQ) {
        const unsigned short* p = Qf + (size_t)i * QDIM + hh * D + d;
        float x0 = bf2f(p[0]), x1 = bf2f(p[128]);
        unsigned short* q = Qb + (size_t)i * QDIM + hh * D + d;
        q[0]   = (unsigned short)f2bf((x0 * cs - x1 * sn) * SCALE);
        q[128] = (unsigned short)f2bf((x1 * cs + x0 * sn) * SCALE);
    } else {
        const unsigned short* p = Kf + (size_t)i * KVDIM + (hh - HQ) * D + d;
        float x0 = bf2f(p[0]), x1 = bf2f(p[128]);
        unsigned short* k = Kb + (size_t)i * KVDIM + (hh - HQ) * D + d;
        k[0]   = (unsigned short)f2bf(x0 * cs - x1 * sn);
        k[128] = (unsigned short)f2bf(x1 * cs + x0 * sn);
    }
}

// ---------------------------------------------------------------------------
// V transpose: Vf [S][KVDIM] bf16 -> Vt [KVDIM][S] bf16.
// ---------------------------------------------------------------------------
__global__ __launch_bounds__(256) void transpose_v(const unsigned short* __restrict__ Vf,
                                                   unsigned short* __restrict__ Vt)
{
    __shared__ float tile[64][65];
    const int s0 = blockIdx.x * 64, d0 = blockIdx.y * 64;
    const int t = threadIdx.x;
    #pragma unroll
    for (int it = 0; it < 4; ++it) {
        int flat = it * 256 + t;
        int r  = flat >> 4;
        int c4 = (flat & 15) * 4;
        uint2 v = *(const uint2*)(Vf + (size_t)(s0 + r) * KVDIM + d0 + c4);
        tile[r][c4 + 0] = bf2f(v.x & 0xffffu); tile[r][c4 + 1] = bf2f(v.x >> 16);
        tile[r][c4 + 2] = bf2f(v.y & 0xffffu); tile[r][c4 + 3] = bf2f(v.y >> 16);
    }
    __syncthreads();
    #pragma unroll
    for (int it = 0; it < 4; ++it) {
        int flat = it * 256 + t;
        int dr  = flat >> 4;
        int sc4 = (flat & 15) * 4;
        uint2 o;
        o.x = f2bf(tile[sc4 + 0][dr]) | (f2bf(tile[sc4 + 1][dr]) << 16);
        o.y = f2bf(tile[sc4 + 2][dr]) | (f2bf(tile[sc4 + 3][dr]) << 16);
        *(uint2*)(Vt + (size_t)(d0 + dr) * S + s0 + sc4) = o;
    }
}

// ---------------------------------------------------------------------------
// MFMA flash attention, double-buffered. Block = 256 threads (4 waves),
// 128 q-rows, 1 head. Wave w: q rows [i0+32w, i0+32w+32). KV tiles of 64 keys,
// staged via global_load_lds into fragment-major LDS; tile j+1 prefetched
// while computing tile j; ONE barrier per tile. P LDS round-trip
// (C-layout -> A-layout). LDS = 2*32K (K) + 2*32K (V) + 16K (P) = 144 KiB.
// ---------------------------------------------------------------------------
__global__ __launch_bounds__(256) void attn_kernel(const unsigned short* __restrict__ Qb,
                                                   const unsigned short* __restrict__ Kb,
                                                   const unsigned short* __restrict__ Vt,
                                                   unsigned short* __restrict__ O)
{
    __shared__ unsigned short Ks[2][64 * 256];   // frag(nt*8+ks): K[key=nt*16+n16][k=ks*32+quad*8]
    __shared__ unsigned short Vs[2][256 * 64];   // frag(dt*2+ks2): Vt[d=dt*16+n16][key=ks2*32+quad*8]
    __shared__ unsigned short Ps[4 * 2048];      // per-wave frag(mt*2+ks2): P[m][key]
    const int t = threadIdx.x;
    const int h = blockIdx.y, kvh = h >> 1;
    const int i0 = blockIdx.x * 128;
    const int w = t >> 6, lid = t & 63, n16 = lid & 15, quad = lid >> 4;
    const int qbase = i0 + w * 32;
    unsigned short* Pw = Ps + w * 2048;

    auto stage = [&](int buf, int j0) {
        #pragma unroll
        for (int it = 0; it < 8; ++it) {          // K (32 KiB)
            int f = it * 4 + w;                   // wave-uniform
            int nt = f >> 3, ks = f & 7;
            glls16(Kb + (size_t)(j0 + nt * 16 + n16) * KVDIM + kvh * D + ks * 32 + quad * 8,
                   &Ks[buf][f * 512]);
        }
        #pragma unroll
        for (int it = 0; it < 8; ++it) {          // V^T (32 KiB)
            int f = it * 4 + w;
            int dt = f >> 1, ks2 = f & 1;
            glls16(Vt + (size_t)(kvh * D + dt * 16 + n16) * S + j0 + ks2 * 32 + quad * 8,
                   &Vs[buf][f * 512]);
        }
    };

    // Q A-frags in registers: qf[mt][ks]
    short8 qf[2][8];
    #pragma unroll
    for (int mt = 0; mt < 2; ++mt)
        #pragma unroll
        for (int ks = 0; ks < 8; ++ks)
            qf[mt][ks] = *(const short8*)(Qb + (size_t)(qbase + mt * 16 + n16) * QDIM + h * D + ks * 32 + quad * 8);

    float m_old[2][4], l[2][4];
    #pragma unroll
    for (int mt = 0; mt < 2; ++mt)
        #pragma unroll
        for (int rg = 0; rg < 4; ++rg) { m_old[mt][rg] = -INFINITY; l[mt][rg] = 0.f; }
    f32x4 Oacc[2][16] = {};

    const int jt_min = (i0 >= SW) ? ((i0 - (SW - 1)) >> 6) : 0;
    const int jt_max = (i0 + 127) >> 6;

    stage(0, jt_min * 64);
    int cur = 0;

    for (int jt = jt_min; jt <= jt_max; ++jt) {
        const int j0 = jt * 64;
        asm volatile("s_waitcnt vmcnt(0)" ::: "memory");   // own staging (issued last iter) done
        __syncthreads();                                   // all waves' staging visible
        if (jt < jt_max) stage(cur ^ 1, (jt + 1) * 64);    // prefetch next KV tile

        // ---- S = Q K^T
        f32x4 sc[2][4] = {};
        #pragma unroll
        for (int ks = 0; ks < 8; ++ks) {
            #pragma unroll
            for (int nt = 0; nt < 4; ++nt) {
                short8 kf = *(const short8*)(&Ks[cur][(nt * 8 + ks) * 512 + lid * 8]);
                sc[0][nt] = __builtin_amdgcn_mfma_f32_16x16x32_bf16(qf[0][ks], kf, sc[0][nt], 0, 0, 0);
                sc[1][nt] = __builtin_amdgcn_mfma_f32_16x16x32_bf16(qf[1][ks], kf, sc[1][nt], 0, 0, 0);
            }
        }

        // ---- softcap + mask (C layout: key = nt*16+n16, q-row = mt*16+quad*4+rg)
        #pragma unroll
        for (int mt = 0; mt < 2; ++mt) {
            #pragma unroll
            for (int nt = 0; nt < 4; ++nt) {
                int j = j0 + nt * 16 + n16;
                #pragma unroll
                for (int rg = 0; rg < 4; ++rg) {
                    int iq = qbase + mt * 16 + quad * 4 + rg;
                    float x = sc[mt][nt][rg];
                    float e = __expf(x * (2.0f / SOFTCAP));
                    x = SOFTCAP * (1.0f - 2.0f / (e + 1.0f));    // 50*tanh(x/50)
                    bool ok = (j <= iq) && (iq - j < SW);
                    sc[mt][nt][rg] = ok ? x : -1e9f;
                }
            }
        }

        // ---- online softmax per q-row
        float alpha[2][4];
        #pragma unroll
        for (int mt = 0; mt < 2; ++mt) {
            #pragma unroll
            for (int rg = 0; rg < 4; ++rg) {
                float mx = fmaxf(fmaxf(sc[mt][0][rg], sc[mt][1][rg]),
                                 fmaxf(sc[mt][2][rg], sc[mt][3][rg]));
                mx = fmaxf(mx, __shfl_xor(mx, 1));
                mx = fmaxf(mx, __shfl_xor(mx, 2));
                mx = fmaxf(mx, __shfl_xor(mx, 4));
                mx = fmaxf(mx, __shfl_xor(mx, 8));
                float mnew = fmaxf(m_old[mt][rg], mx);
                alpha[mt][rg] = __expf(m_old[mt][rg] - mnew);   // -inf -> 0 first tile
                m_old[mt][rg] = mnew;
            }
        }
        // ---- p = exp(s-m), write P to LDS in A-frag order, accumulate l
        #pragma unroll
        for (int mt = 0; mt < 2; ++mt) {
            #pragma unroll
            for (int rg = 0; rg < 4; ++rg) {
                float rs = 0.f;
                #pragma unroll
                for (int nt = 0; nt < 4; ++nt) {
                    float pv = __expf(sc[mt][nt][rg] - m_old[mt][rg]);
                    // frag(mt, ks2=nt>>1); lane' = (quad*4+rg) + 16*((nt&1)*2 + (n16>>3)); elem = n16&7
                    Pw[(mt * 2 + (nt >> 1)) * 512
                       + (quad * 4 + rg + 16 * ((nt & 1) * 2 + (n16 >> 3))) * 8
                       + (n16 & 7)] = (unsigned short)f2bf(pv);
                    rs += pv;
                }
                rs += __shfl_xor(rs, 1); rs += __shfl_xor(rs, 2);
                rs += __shfl_xor(rs, 4); rs += __shfl_xor(rs, 8);
                l[mt][rg] = l[mt][rg] * alpha[mt][rg] + rs;
            }
        }
        #pragma unroll
        for (int mt = 0; mt < 2; ++mt)
            #pragma unroll
            for (int dt = 0; dt < 16; ++dt)
                #pragma unroll
                for (int rg = 0; rg < 4; ++rg)
                    Oacc[mt][dt][rg] *= alpha[mt][rg];

        asm volatile("s_waitcnt lgkmcnt(0)" ::: "memory");   // P writes visible (wave-private)

        // ---- O += P V
        #pragma unroll
        for (int ks2 = 0; ks2 < 2; ++ks2) {
            short8 pf0 = *(const short8*)(Pw + (0 * 2 + ks2) * 512 + lid * 8);
            short8 pf1 = *(const short8*)(Pw + (1 * 2 + ks2) * 512 + lid * 8);
            #pragma unroll
            for (int dt = 0; dt < 16; ++dt) {
                short8 vf = *(const short8*)(&Vs[cur][(dt * 2 + ks2) * 512 + lid * 8]);
                Oacc[0][dt] = __builtin_amdgcn_mfma_f32_16x16x32_bf16(pf0, vf, Oacc[0][dt], 0, 0, 0);
                Oacc[1][dt] = __builtin_amdgcn_mfma_f32_16x16x32_bf16(pf1, vf, Oacc[1][dt], 0, 0, 0);
            }
        }
        cur ^= 1;
    }

    #pragma unroll
    for (int mt = 0; mt < 2; ++mt)
        #pragma unroll
        for (int rg = 0; rg < 4; ++rg) l[mt][rg] = 1.0f / l[mt][rg];
    #pragma unroll
    for (int mt = 0; mt < 2; ++mt) {
        #pragma unroll
        for (int dt = 0; dt < 16; ++dt) {
            int col = h * D + dt * 16 + n16;
            #pragma unroll
            for (int rg = 0; rg < 4; ++rg) {
                int row = qbase + mt * 16 + quad * 4 + rg;
                O[(size_t)row * QDIM + col] = (unsigned short)f2bf(Oacc[mt][dt][rg] * l[mt][rg]);
            }
        }
    }
}

extern "C" void kernel_launch(void* const* d_in, const int* in_sizes, int n_in,
                              void* d_out, int out_size, void* d_ws, size_t ws_size,
                              hipStream_t stream) {
    const float* hidden = (const float*)d_in[0];
    // d_in[1] = attention_mask: recomputed analytically, not read
    const float* Wq = (const float*)d_in[2];
    const float* Wk = (const float*)d_in[3];
    const float* Wv = (const float*)d_in[4];
    const float* Wo = (const float*)d_in[5];
    const int* pos = (const int*)d_in[6];
    float* out = (float*)d_out;

    char* ws = (char*)d_ws;
    unsigned short* Qf = (unsigned short*)(ws);                       // [S][2048] bf16, 16 MiB
    unsigned short* Kf = (unsigned short*)(ws + (size_t)(16 << 20));  // [S][1024] bf16,  8 MiB
    unsigned short* Vf = (unsigned short*)(ws + (size_t)(24 << 20));  // [S][1024] bf16,  8 MiB
    unsigned short* Qb = (unsigned short*)(ws + (size_t)(32 << 20));  // 16 MiB
    unsigned short* Kb = (unsigned short*)(ws + (size_t)(48 << 20));  //  8 MiB
    unsigned short* Vt = (unsigned short*)(ws + (size_t)(56 << 20));  //  8 MiB
    unsigned short* Hb = (unsigned short*)(ws + (size_t)(64 << 20));  // [S][2304] bf16, 18 MiB
    unsigned short* Wb = (unsigned short*)(ws + (size_t)(82 << 20));  // weight buf (reused), 9 MiB
    unsigned short* Oa = (unsigned short*)(ws);                       // aliases Qf (dead after rope)

    cvt_bf16<<<(S * HID) / 1024, 256, 0, stream>>>(hidden, Hb);

    cvt_bf16<<<(QDIM * HID) / 1024, 256, 0, stream>>>(Wq, Wb);
    bf16_gemm_bt<unsigned short><<<dim3(QDIM / 128, S / 128), 256, 0, stream>>>(Hb, Wb, Qf, S, QDIM, HID);
    cvt_bf16<<<(KVDIM * HID) / 1024, 256, 0, stream>>>(Wk, Wb);
    bf16_gemm_bt<unsigned short><<<dim3(KVDIM / 128, S / 128), 256, 0, stream>>>(Hb, Wb, Kf, S, KVDIM, HID);
    cvt_bf16<<<(KVDIM * HID) / 1024, 256, 0, stream>>>(Wv, Wb);
    bf16_gemm_bt<unsigned short><<<dim3(KVDIM / 128, S / 128), 256, 0, stream>>>(Hb, Wb, Vf, S, KVDIM, HID);

    rope_kernel<<<(S * 12 * 128) / 256, 256, 0, stream>>>(Qf, Kf, Qb, Kb, pos);
    transpose_v<<<dim3(S / 64, KVDIM / 64), 256, 0, stream>>>(Vf, Vt);

    attn_kernel<<<dim3(S / 128, HQ), 256, 0, stream>>>(Qb, Kb, Vt, Oa);

    cvt_bf16<<<(HID * QDIM) / 1024, 256, 0, stream>>>(Wo, Wb);
    bf16_gemm_bt<float><<<dim3(HID / 128, S / 128), 256, 0, stream>>>(Oa, Wb, out, S, HID, QDIM);
}